// Round 1
// baseline (125.086 us; speedup 1.0000x reference)
//
#include <hip/hip_runtime.h>
#include <hip/hip_bf16.h>

// MXFP8Linear: out[n,j] = sum_b sx[n,b]*sw[j,b]*dot32(fp8(x),fp8(w)) + bias[j]
// Strategy: quantize->dequantize both matrices to bf16 with scales folded in
// (exact fp8 products survive; bf16 rounding adds ~2^-9 rel err, far under
// threshold), then a single bf16 MFMA GEMM (A * B^T layout, both K-contig).

typedef __attribute__((ext_vector_type(8))) __bf16 bf16x8;
typedef __attribute__((ext_vector_type(4))) float f32x4;

#define NMAT 2048
#define ROWB 4096   /* bytes per bf16 row */
#define FP8_MAX 448.0f

__device__ inline unsigned short bfbits(float f) {
  union { __hip_bfloat16 h; unsigned short u; } cv;
  cv.h = __float2bfloat16(f);
  return cv.u;
}

// quantize a,b to fp8 e4m3 (HW RNE, OCP on gfx950), dequant, pack 2 bf16
__device__ inline unsigned pack2(float a, float b, float scale) {
  int p = __builtin_amdgcn_cvt_pk_fp8_f32(a / scale, b / scale, 0, false);
  float qa = __builtin_amdgcn_cvt_f32_fp8(p, 0) * scale;
  float qb = __builtin_amdgcn_cvt_f32_fp8(p, 1) * scale;
  return (unsigned)bfbits(qa) | ((unsigned)bfbits(qb) << 16);
}

// one thread = one 32-element block: amax -> scale -> qdq -> bf16 store (64B)
__global__ __launch_bounds__(256) void qdq_kernel(const float* __restrict__ in,
                                                  unsigned* __restrict__ out) {
  int b = blockIdx.x * 256 + threadIdx.x;
  const float4* p = (const float4*)(in + (size_t)b * 32);
  float4 v[8];
  float amax = 0.f;
#pragma unroll
  for (int i = 0; i < 8; ++i) {
    v[i] = p[i];
    amax = fmaxf(amax, fmaxf(fmaxf(fabsf(v[i].x), fabsf(v[i].y)),
                             fmaxf(fabsf(v[i].z), fabsf(v[i].w))));
  }
  float scale = fmaxf(amax / FP8_MAX, 1e-30f);  // real div to match reference
  unsigned r[16];
#pragma unroll
  for (int i = 0; i < 8; ++i) {
    r[2 * i]     = pack2(v[i].x, v[i].y, scale);
    r[2 * i + 1] = pack2(v[i].z, v[i].w, scale);
  }
  uint4* dst = (uint4*)(out + (size_t)b * 16);
  dst[0] = make_uint4(r[0], r[1], r[2], r[3]);
  dst[1] = make_uint4(r[4], r[5], r[6], r[7]);
  dst[2] = make_uint4(r[8], r[9], r[10], r[11]);
  dst[3] = make_uint4(r[12], r[13], r[14], r[15]);
}

// C[n,j] = sum_k A[n,k]*B[j,k] + bias[j]; 128x128 tile, 8 waves, wave=64x32
__global__ __launch_bounds__(512) void gemm_kernel(const __bf16* __restrict__ A,
                                                   const __bf16* __restrict__ B,
                                                   const float* __restrict__ bias,
                                                   float* __restrict__ C) {
  __shared__ __align__(16) __bf16 As[128 * 32];
  __shared__ __align__(16) __bf16 Bs[128 * 32];
  const int tid  = threadIdx.x;
  const int lane = tid & 63;
  const int wid  = tid >> 6;
  const int wr   = wid >> 2;   // 0..1 -> row offset wr*64
  const int wc   = wid & 3;    // 0..3 -> col offset wc*32
  const int row0 = blockIdx.y * 128;
  const int col0 = blockIdx.x * 128;

  // staging: 512 threads x 16B = 8KB = one [128][32] bf16 tile (linear LDS)
  const int o  = tid * 16;     // byte offset in tile
  const int sr = o >> 6;       // tile row
  const int sc = o & 63;       // byte col within 64B row
  const char* Ag = (const char*)A + (size_t)(row0 + sr) * ROWB + sc;
  const char* Bg = (const char*)B + (size_t)(col0 + sr) * ROWB + sc;
  char* Al = (char*)As + o;
  char* Bl = (char*)Bs + o;

  const int l15 = lane & 15;
  const int kg  = (lane >> 4) * 8;  // k-element offset of this lane's 8 elems
  const __bf16* Ard = As + (wr * 64 + l15) * 32 + kg;
  const __bf16* Brd = Bs + (wc * 32 + l15) * 32 + kg;

  f32x4 acc[4][2] = {};

  for (int kt = 0; kt < 64; ++kt) {
    __syncthreads();  // previous compute done before overwrite
    __builtin_amdgcn_global_load_lds(
        (const __attribute__((address_space(1))) unsigned*)(Ag + kt * 64),
        (__attribute__((address_space(3))) unsigned*)Al, 16, 0, 0);
    __builtin_amdgcn_global_load_lds(
        (const __attribute__((address_space(1))) unsigned*)(Bg + kt * 64),
        (__attribute__((address_space(3))) unsigned*)Bl, 16, 0, 0);
    __syncthreads();  // staging complete
    bf16x8 af[4], bf[2];
#pragma unroll
    for (int m = 0; m < 4; ++m) af[m] = *(const bf16x8*)(Ard + m * 16 * 32);
#pragma unroll
    for (int n = 0; n < 2; ++n) bf[n] = *(const bf16x8*)(Brd + n * 16 * 32);
#pragma unroll
    for (int m = 0; m < 4; ++m)
#pragma unroll
      for (int n = 0; n < 2; ++n)
        acc[m][n] =
            __builtin_amdgcn_mfma_f32_16x16x32_bf16(af[m], bf[n], acc[m][n], 0, 0, 0);
  }

  // epilogue: C/D layout col=lane&15, row=(lane>>4)*4+reg  [m89 verified]
  const int rb = row0 + wr * 64 + (lane >> 4) * 4;
#pragma unroll
  for (int n = 0; n < 2; ++n) {
    const int j = col0 + wc * 32 + n * 16 + l15;
    const float bv = bias[j];
#pragma unroll
    for (int m = 0; m < 4; ++m) {
#pragma unroll
      for (int r = 0; r < 4; ++r) {
        C[(size_t)(rb + m * 16 + r) * NMAT + j] = acc[m][n][r] + bv;
      }
    }
  }
}

extern "C" void kernel_launch(void* const* d_in, const int* in_sizes, int n_in,
                              void* d_out, int out_size, void* d_ws, size_t ws_size,
                              hipStream_t stream) {
  const float* x  = (const float*)d_in[0];
  const float* w  = (const float*)d_in[1];
  const float* bs = (const float*)d_in[2];
  float* out = (float*)d_out;

  unsigned* xd = (unsigned*)d_ws;                 // 2048x2048 bf16 = 8MB
  unsigned* wd = xd + (NMAT * NMAT / 2);          // next 8MB

  qdq_kernel<<<dim3(NMAT * (NMAT / 32) / 256), dim3(256), 0, stream>>>(x, xd);
  qdq_kernel<<<dim3(NMAT * (NMAT / 32) / 256), dim3(256), 0, stream>>>(w, wd);

  dim3 grid(NMAT / 128, NMAT / 128);
  gemm_kernel<<<grid, dim3(512), 0, stream>>>((const __bf16*)xd, (const __bf16*)wd,
                                              bs, out);
}

// Round 2
// 107.314 us; speedup vs baseline: 1.1656x; 1.1656x over previous
//
#include <hip/hip_runtime.h>
#include <hip/hip_bf16.h>

// MXFP8Linear: out[n,j] = sum_b sx[n,b]*sw[j,b]*dot32(fp8(x),fp8(w)) + bias[j]
// Strategy: qdq both matrices to bf16 with scales folded in, then bf16 MFMA
// GEMM (A * B^T, both K-contig). R1: coalesced qdq + 2-phase dbuf GEMM (BK=64,
// XOR-swizzled LDS via pre-swizzled global source).

typedef __attribute__((ext_vector_type(8))) __bf16 bf16x8;
typedef __attribute__((ext_vector_type(4))) float f32x4;

#define NMAT 2048
#define FP8_MAX 448.0f

__device__ inline unsigned short bfbits(float f) {
  union { __hip_bfloat16 h; unsigned short u; } cv;
  cv.h = __float2bfloat16(f);
  return cv.u;
}

// quantize a,b to fp8 e4m3 (HW RNE, OCP on gfx950), dequant, pack 2 bf16
__device__ inline unsigned pack2(float a, float b, float scale) {
  int p = __builtin_amdgcn_cvt_pk_fp8_f32(a / scale, b / scale, 0, false);
  float qa = __builtin_amdgcn_cvt_f32_fp8(p, 0) * scale;
  float qb = __builtin_amdgcn_cvt_f32_fp8(p, 1) * scale;
  return (unsigned)bfbits(qa) | ((unsigned)bfbits(qb) << 16);
}

// Coalesced qdq: lane loads float4 coalesced; 32-block = 8 consecutive lanes;
// amax via shfl_xor(1,2,4); 8B/lane coalesced store. One launch for x and w.
__global__ __launch_bounds__(256) void qdq_kernel(const float* __restrict__ x,
                                                  uint2* __restrict__ xo,
                                                  const float* __restrict__ w,
                                                  uint2* __restrict__ wo) {
  int g = blockIdx.x;
  const float* in;
  uint2* out;
  if (g >= 4096) { in = w; out = wo; g -= 4096; }
  else           { in = x; out = xo; }
  const int t = threadIdx.x;
  const size_t base = (size_t)g * 1024;  // floats per workgroup
  float4 v = ((const float4*)(in + base))[t];
  float amax = fmaxf(fmaxf(fabsf(v.x), fabsf(v.y)), fmaxf(fabsf(v.z), fabsf(v.w)));
  amax = fmaxf(amax, __shfl_xor(amax, 1));
  amax = fmaxf(amax, __shfl_xor(amax, 2));
  amax = fmaxf(amax, __shfl_xor(amax, 4));
  float scale = fmaxf(amax / FP8_MAX, 1e-30f);  // real div to match reference
  uint2 r;
  r.x = pack2(v.x, v.y, scale);
  r.y = pack2(v.z, v.w, scale);
  out[base / 4 + t] = r;
}

// C[n,j] = sum_k A[n,k]*B[j,k] + bias[j]
// 128x128 tile, 512 thr (8 waves 2Mx4N, wave tile 64x32), BK=64,
// double-buffered LDS (64KB), one barrier per K-tile (2-phase pipeline).
// LDS swizzle: LDS[r][c ^ ((r&7)<<4)] = G[r][c]; staging pre-swizzles the
// GLOBAL source (global_load_lds dest must stay linear), reads apply the XOR.
__global__ __launch_bounds__(512) void gemm_kernel(const __bf16* __restrict__ A,
                                                   const __bf16* __restrict__ B,
                                                   const float* __restrict__ bias,
                                                   float* __restrict__ C) {
  __shared__ __align__(16) char lds[65536];  // [buf][A 16K | B 16K]
  const int tid  = threadIdx.x;
  const int lane = tid & 63;
  const int wid  = tid >> 6;
  const int wr   = wid >> 2;   // 0..1
  const int wc   = wid & 3;    // 0..3
  const int row0 = blockIdx.y * 128;
  const int col0 = blockIdx.x * 128;

  // ---- staging: 2 issues per matrix (512 thr x 16B = 8KB; tile = 16KB) ----
  const int oA0 = tid * 16;        // linear dest byte in tile, issue 0
  const int oA1 = oA0 + 8192;      // issue 1
  const int r0 = oA0 >> 7, r1 = oA1 >> 7;
  const int c0 = (oA0 & 127) ^ ((r0 & 7) << 4);  // pre-swizzled source col
  const int c1 = (oA1 & 127) ^ ((r1 & 7) << 4);
  const char* AgS0 = (const char*)A + (size_t)(row0 + r0) * 4096 + c0;
  const char* AgS1 = (const char*)A + (size_t)(row0 + r1) * 4096 + c1;
  const char* BgS0 = (const char*)B + (size_t)(col0 + r0) * 4096 + c0;
  const char* BgS1 = (const char*)B + (size_t)(col0 + r1) * 4096 + c1;

#define STAGE(buf, kt) do {                                                      \
    const int kb = (kt) * 128;                                                   \
    char* lb = lds + (buf) * 32768;                                              \
    __builtin_amdgcn_global_load_lds(                                            \
        (const __attribute__((address_space(1))) unsigned*)(AgS0 + kb),          \
        (__attribute__((address_space(3))) unsigned*)(lb + oA0), 16, 0, 0);      \
    __builtin_amdgcn_global_load_lds(                                            \
        (const __attribute__((address_space(1))) unsigned*)(AgS1 + kb),          \
        (__attribute__((address_space(3))) unsigned*)(lb + oA1), 16, 0, 0);      \
    __builtin_amdgcn_global_load_lds(                                            \
        (const __attribute__((address_space(1))) unsigned*)(BgS0 + kb),          \
        (__attribute__((address_space(3))) unsigned*)(lb + 16384 + oA0), 16, 0, 0);\
    __builtin_amdgcn_global_load_lds(                                            \
        (const __attribute__((address_space(1))) unsigned*)(BgS1 + kb),          \
        (__attribute__((address_space(3))) unsigned*)(lb + 16384 + oA1), 16, 0, 0);\
  } while (0)

  // ---- fragment read addressing (swizzled) ----
  const int l15 = lane & 15;
  const int q16 = (lane >> 4) * 16;        // 16B sub-chunk within 32-k step
  const int swz = (l15 & 7) << 4;          // r&7 == l15&7 (row offsets %8==0)
  const int ck0 = q16 ^ swz;               // kk=0 byte col (swizzled)
  const int ck1 = (64 + q16) ^ swz;        // kk=1
  const int aRow = (wr * 64 + l15) * 128;  // byte row base for A frags
  const int bRow = (wc * 32 + l15) * 128;  // byte row base for B frags

  f32x4 acc[4][2] = {};

  auto compute = [&](const int buf) {
    const char* ab = lds + buf * 32768;
    const char* bb = ab + 16384;
    bf16x8 a0[4], a1[4], b0[2], b1[2];
#pragma unroll
    for (int m = 0; m < 4; ++m) {
      a0[m] = *(const bf16x8*)(ab + aRow + m * 2048 + ck0);
      a1[m] = *(const bf16x8*)(ab + aRow + m * 2048 + ck1);
    }
#pragma unroll
    for (int n = 0; n < 2; ++n) {
      b0[n] = *(const bf16x8*)(bb + bRow + n * 2048 + ck0);
      b1[n] = *(const bf16x8*)(bb + bRow + n * 2048 + ck1);
    }
#pragma unroll
    for (int m = 0; m < 4; ++m)
#pragma unroll
      for (int n = 0; n < 2; ++n) {
        acc[m][n] = __builtin_amdgcn_mfma_f32_16x16x32_bf16(a0[m], b0[n], acc[m][n], 0, 0, 0);
        acc[m][n] = __builtin_amdgcn_mfma_f32_16x16x32_bf16(a1[m], b1[n], acc[m][n], 0, 0, 0);
      }
  };

  STAGE(0, 0);
  __syncthreads();
#pragma unroll 1
  for (int t = 0; t < 30; t += 2) {
    STAGE(1, t + 1);
    compute(0);
    __syncthreads();
    STAGE(0, t + 2);
    compute(1);
    __syncthreads();
  }
  STAGE(1, 31);
  compute(0);
  __syncthreads();
  compute(1);

  // epilogue: C/D layout col=lane&15, row=(lane>>4)*4+reg  [m89 verified]
  const int rb = row0 + wr * 64 + (lane >> 4) * 4;
#pragma unroll
  for (int n = 0; n < 2; ++n) {
    const int j = col0 + wc * 32 + n * 16 + l15;
    const float bv = bias[j];
#pragma unroll
    for (int m = 0; m < 4; ++m)
#pragma unroll
      for (int r = 0; r < 4; ++r)
        C[(size_t)(rb + m * 16 + r) * NMAT + j] = acc[m][n][r] + bv;
  }
#undef STAGE
}

extern "C" void kernel_launch(void* const* d_in, const int* in_sizes, int n_in,
                              void* d_out, int out_size, void* d_ws, size_t ws_size,
                              hipStream_t stream) {
  const float* x  = (const float*)d_in[0];
  const float* w  = (const float*)d_in[1];
  const float* bs = (const float*)d_in[2];
  float* out = (float*)d_out;

  uint2* xd = (uint2*)d_ws;                       // 2048x2048 bf16 = 8MB
  uint2* wd = xd + (NMAT * (size_t)NMAT / 4);     // next 8MB

  qdq_kernel<<<dim3(8192), dim3(256), 0, stream>>>(x, xd, w, wd);

  dim3 grid(NMAT / 128, NMAT / 128);
  gemm_kernel<<<grid, dim3(512), 0, stream>>>((const __bf16*)xd, (const __bf16*)wd,
                                              bs, out);
}

// Round 4
// 105.495 us; speedup vs baseline: 1.1857x; 1.0172x over previous
//
#include <hip/hip_runtime.h>
#include <hip/hip_bf16.h>

// MXFP8Linear: out[n,j] = sum_b sx[n,b]*sw[j,b]*dot32(fp8(x),fp8(w)) + bias[j]
// Strategy: qdq both matrices to bf16 with scales folded in, then bf16 MFMA
// GEMM (A * B^T, both K-contig).
// R2: BM=128 BN=64, 4 waves, grid=512 WGs -> 2 blocks/CU (inter-block overlap
// hides barrier drains; at N=2048 the 128x128 grid was 1 block/CU = no hiding).
// R3: identical resubmit (R2 bench was lost to GPU acquisition timeout).

typedef __attribute__((ext_vector_type(8))) __bf16 bf16x8;
typedef __attribute__((ext_vector_type(4))) float f32x4;

#define NMAT 2048
#define FP8_MAX 448.0f

__device__ inline unsigned short bfbits(float f) {
  union { __hip_bfloat16 h; unsigned short u; } cv;
  cv.h = __float2bfloat16(f);
  return cv.u;
}

// quantize a,b to fp8 e4m3 (HW RNE, OCP on gfx950), dequant, pack 2 bf16
__device__ inline unsigned pack2(float a, float b, float scale) {
  int p = __builtin_amdgcn_cvt_pk_fp8_f32(a / scale, b / scale, 0, false);
  float qa = __builtin_amdgcn_cvt_f32_fp8(p, 0) * scale;
  float qb = __builtin_amdgcn_cvt_f32_fp8(p, 1) * scale;
  return (unsigned)bfbits(qa) | ((unsigned)bfbits(qb) << 16);
}

// Coalesced qdq: lane loads float4 coalesced; 32-block = 8 consecutive lanes;
// amax via shfl_xor(1,2,4); 8B/lane coalesced store. One launch for x and w.
__global__ __launch_bounds__(256) void qdq_kernel(const float* __restrict__ x,
                                                  uint2* __restrict__ xo,
                                                  const float* __restrict__ w,
                                                  uint2* __restrict__ wo) {
  int g = blockIdx.x;
  const float* in;
  uint2* out;
  if (g >= 4096) { in = w; out = wo; g -= 4096; }
  else           { in = x; out = xo; }
  const int t = threadIdx.x;
  const size_t base = (size_t)g * 1024;  // floats per workgroup
  float4 v = ((const float4*)(in + base))[t];
  float amax = fmaxf(fmaxf(fabsf(v.x), fabsf(v.y)), fmaxf(fabsf(v.z), fabsf(v.w)));
  amax = fmaxf(amax, __shfl_xor(amax, 1));
  amax = fmaxf(amax, __shfl_xor(amax, 2));
  amax = fmaxf(amax, __shfl_xor(amax, 4));
  float scale = fmaxf(amax / FP8_MAX, 1e-30f);  // real div to match reference
  uint2 r;
  r.x = pack2(v.x, v.y, scale);
  r.y = pack2(v.z, v.w, scale);
  out[base / 4 + t] = r;
}

// C[n,j] = sum_k A[n,k]*B[j,k] + bias[j]
// BM=128 BN=64 BK=64, 256 thr (4 waves 2Mx2N, wave tile 64x32), dbuf LDS 48KB,
// one barrier per K-tile (2-phase). grid (32,16) = 512 WGs = 2 blocks/CU.
// LDS swizzle: LDS[r][c ^ ((r&7)<<4)] = G[r][c]; staging pre-swizzles the
// GLOBAL source (global_load_lds dest must stay linear), reads apply the XOR.
__global__ __launch_bounds__(256) void gemm_kernel(const __bf16* __restrict__ A,
                                                   const __bf16* __restrict__ B,
                                                   const float* __restrict__ bias,
                                                   float* __restrict__ C) {
  __shared__ __align__(16) char lds[49152];  // [buf][A 16K | B 8K]
  const int tid  = threadIdx.x;
  const int lane = tid & 63;
  const int wid  = tid >> 6;
  const int wr   = wid >> 1;   // 0..1 -> row offset wr*64
  const int wc   = wid & 1;    // 0..1 -> col offset wc*32
  const int row0 = blockIdx.y * 128;
  const int col0 = blockIdx.x * 64;

  // ---- staging: A = 4 issues, B = 2 issues (256 thr x 16B = 4KB each) ----
  // issue i covers linear tile bytes [i*4096, (i+1)*4096); rows are 128B.
  int rS[4], cS[4];
#pragma unroll
  for (int i = 0; i < 4; ++i) {
    const int o = i * 4096 + tid * 16;
    rS[i] = o >> 7;
    cS[i] = (o & 127) ^ ((rS[i] & 7) << 4);  // pre-swizzled source col
  }
  const char* AgS[4];
  const char* BgS[2];
#pragma unroll
  for (int i = 0; i < 4; ++i)
    AgS[i] = (const char*)A + (size_t)(row0 + rS[i]) * 4096 + cS[i];
#pragma unroll
  for (int j = 0; j < 2; ++j)
    BgS[j] = (const char*)B + (size_t)(col0 + rS[j]) * 4096 + cS[j];
  const int dst = tid * 16;

#define STAGE(buf, kt) do {                                                      \
    const int kb = (kt) * 128;                                                   \
    char* lb = lds + (buf) * 24576;                                              \
    _Pragma("unroll")                                                            \
    for (int i = 0; i < 4; ++i)                                                  \
      __builtin_amdgcn_global_load_lds(                                          \
          (const __attribute__((address_space(1))) unsigned*)(AgS[i] + kb),      \
          (__attribute__((address_space(3))) unsigned*)(lb + i * 4096 + dst),    \
          16, 0, 0);                                                             \
    _Pragma("unroll")                                                            \
    for (int j = 0; j < 2; ++j)                                                  \
      __builtin_amdgcn_global_load_lds(                                          \
          (const __attribute__((address_space(1))) unsigned*)(BgS[j] + kb),      \
          (__attribute__((address_space(3))) unsigned*)(lb + 16384 + j * 4096 + dst), \
          16, 0, 0);                                                             \
  } while (0)

  // ---- fragment read addressing (swizzled) ----
  const int l15 = lane & 15;
  const int q16 = (lane >> 4) * 16;        // 16B sub-chunk within 32-k step
  const int swz = (l15 & 7) << 4;          // row&7 == l15&7 (row offsets %8==0)
  const int ck0 = q16 ^ swz;               // kk=0 byte col (swizzled)
  const int ck1 = (64 + q16) ^ swz;        // kk=1
  const int aRow = (wr * 64 + l15) * 128;  // byte row base for A frags
  const int bRow = (wc * 32 + l15) * 128;  // byte row base for B frags

  f32x4 acc[4][2] = {};

  auto compute = [&](const int buf) {
    const char* ab = lds + buf * 24576;
    const char* bb = ab + 16384;
    bf16x8 a0[4], a1[4], b0[2], b1[2];
#pragma unroll
    for (int m = 0; m < 4; ++m) {
      a0[m] = *(const bf16x8*)(ab + aRow + m * 2048 + ck0);
      a1[m] = *(const bf16x8*)(ab + aRow + m * 2048 + ck1);
    }
#pragma unroll
    for (int n = 0; n < 2; ++n) {
      b0[n] = *(const bf16x8*)(bb + bRow + n * 2048 + ck0);
      b1[n] = *(const bf16x8*)(bb + bRow + n * 2048 + ck1);
    }
#pragma unroll
    for (int m = 0; m < 4; ++m)
#pragma unroll
      for (int n = 0; n < 2; ++n) {
        acc[m][n] = __builtin_amdgcn_mfma_f32_16x16x32_bf16(a0[m], b0[n], acc[m][n], 0, 0, 0);
        acc[m][n] = __builtin_amdgcn_mfma_f32_16x16x32_bf16(a1[m], b1[n], acc[m][n], 0, 0, 0);
      }
  };

  STAGE(0, 0);
  __syncthreads();
#pragma unroll 1
  for (int t = 0; t < 30; t += 2) {
    STAGE(1, t + 1);
    compute(0);
    __syncthreads();
    STAGE(0, t + 2);
    compute(1);
    __syncthreads();
  }
  STAGE(1, 31);
  compute(0);
  __syncthreads();
  compute(1);

  // epilogue: C/D layout col=lane&15, row=(lane>>4)*4+reg  [m89 verified]
  const int rb = row0 + wr * 64 + (lane >> 4) * 4;
#pragma unroll
  for (int n = 0; n < 2; ++n) {
    const int j = col0 + wc * 32 + n * 16 + l15;
    const float bv = bias[j];
#pragma unroll
    for (int m = 0; m < 4; ++m)
#pragma unroll
      for (int r = 0; r < 4; ++r)
        C[(size_t)(rb + m * 16 + r) * NMAT + j] = acc[m][n][r] + bv;
  }
#undef STAGE
}

extern "C" void kernel_launch(void* const* d_in, const int* in_sizes, int n_in,
                              void* d_out, int out_size, void* d_ws, size_t ws_size,
                              hipStream_t stream) {
  const float* x  = (const float*)d_in[0];
  const float* w  = (const float*)d_in[1];
  const float* bs = (const float*)d_in[2];
  float* out = (float*)d_out;

  uint2* xd = (uint2*)d_ws;                       // 2048x2048 bf16 = 8MB
  uint2* wd = xd + (NMAT * (size_t)NMAT / 4);     // next 8MB

  qdq_kernel<<<dim3(8192), dim3(256), 0, stream>>>(x, xd, w, wd);

  dim3 grid(NMAT / 64, NMAT / 128);
  gemm_kernel<<<grid, dim3(256), 0, stream>>>((const __bf16*)xd, (const __bf16*)wd,
                                              bs, out);
}

// Round 5
// 104.072 us; speedup vs baseline: 1.2019x; 1.0137x over previous
//
#include <hip/hip_runtime.h>
#include <hip/hip_bf16.h>

// MXFP8Linear: out[n,j] = sum_b sx[n,b]*sw[j,b]*dot32(fp8(x),fp8(w)) + bias[j]
// Strategy: qdq both matrices to bf16 with scales folded in, then bf16 MFMA
// GEMM (A * B^T, both K-contig).
// R2: BM=128 BN=64, 4 waves, grid=512 WGs -> 2 blocks/CU.
// R5: T4 counted vmcnt — replace __syncthreads with raw s_barrier pairs and
// `s_waitcnt vmcnt(6)` so the next tile's 6 global_load_lds stay in flight
// across the barriers (never drain to 0 in the main loop).

typedef __attribute__((ext_vector_type(8))) __bf16 bf16x8;
typedef __attribute__((ext_vector_type(4))) float f32x4;

#define NMAT 2048
#define FP8_MAX 448.0f

__device__ inline unsigned short bfbits(float f) {
  union { __hip_bfloat16 h; unsigned short u; } cv;
  cv.h = __float2bfloat16(f);
  return cv.u;
}

// quantize a,b to fp8 e4m3 (HW RNE, OCP on gfx950), dequant, pack 2 bf16
__device__ inline unsigned pack2(float a, float b, float scale) {
  int p = __builtin_amdgcn_cvt_pk_fp8_f32(a / scale, b / scale, 0, false);
  float qa = __builtin_amdgcn_cvt_f32_fp8(p, 0) * scale;
  float qb = __builtin_amdgcn_cvt_f32_fp8(p, 1) * scale;
  return (unsigned)bfbits(qa) | ((unsigned)bfbits(qb) << 16);
}

// Coalesced qdq: lane loads float4 coalesced; 32-block = 8 consecutive lanes;
// amax via shfl_xor(1,2,4); 8B/lane coalesced store. One launch for x and w.
__global__ __launch_bounds__(256) void qdq_kernel(const float* __restrict__ x,
                                                  uint2* __restrict__ xo,
                                                  const float* __restrict__ w,
                                                  uint2* __restrict__ wo) {
  int g = blockIdx.x;
  const float* in;
  uint2* out;
  if (g >= 4096) { in = w; out = wo; g -= 4096; }
  else           { in = x; out = xo; }
  const int t = threadIdx.x;
  const size_t base = (size_t)g * 1024;  // floats per workgroup
  float4 v = ((const float4*)(in + base))[t];
  float amax = fmaxf(fmaxf(fabsf(v.x), fabsf(v.y)), fmaxf(fabsf(v.z), fabsf(v.w)));
  amax = fmaxf(amax, __shfl_xor(amax, 1));
  amax = fmaxf(amax, __shfl_xor(amax, 2));
  amax = fmaxf(amax, __shfl_xor(amax, 4));
  float scale = fmaxf(amax / FP8_MAX, 1e-30f);  // real div to match reference
  uint2 r;
  r.x = pack2(v.x, v.y, scale);
  r.y = pack2(v.z, v.w, scale);
  out[base / 4 + t] = r;
}

// C[n,j] = sum_k A[n,k]*B[j,k] + bias[j]
// BM=128 BN=64 BK=64, 256 thr (4 waves 2Mx2N, wave tile 64x32), dbuf LDS 48KB.
// grid (32,16) = 512 WGs = 2 blocks/CU.
// Main loop per K-tile: STAGE(next) ; vmcnt(6) ; s_barrier ; compute(cur) ;
// s_barrier  — counted vmcnt keeps next tile's loads in flight (T4).
// LDS swizzle: LDS[r][c ^ ((r&7)<<4)] = G[r][c]; staging pre-swizzles the
// GLOBAL source (global_load_lds dest must stay linear), reads apply the XOR.
__global__ __launch_bounds__(256) void gemm_kernel(const __bf16* __restrict__ A,
                                                   const __bf16* __restrict__ B,
                                                   const float* __restrict__ bias,
                                                   float* __restrict__ C) {
  __shared__ __align__(16) char lds[49152];  // [buf][A 16K | B 8K]
  const int tid  = threadIdx.x;
  const int lane = tid & 63;
  const int wid  = tid >> 6;
  const int wr   = wid >> 1;   // 0..1 -> row offset wr*64
  const int wc   = wid & 1;    // 0..1 -> col offset wc*32
  const int row0 = blockIdx.y * 128;
  const int col0 = blockIdx.x * 64;

  // ---- staging: A = 4 issues, B = 2 issues (256 thr x 16B = 4KB each) ----
  // issue i covers linear tile bytes [i*4096, (i+1)*4096); rows are 128B.
  int rS[4], cS[4];
#pragma unroll
  for (int i = 0; i < 4; ++i) {
    const int o = i * 4096 + tid * 16;
    rS[i] = o >> 7;
    cS[i] = (o & 127) ^ ((rS[i] & 7) << 4);  // pre-swizzled source col
  }
  const char* AgS[4];
  const char* BgS[2];
#pragma unroll
  for (int i = 0; i < 4; ++i)
    AgS[i] = (const char*)A + (size_t)(row0 + rS[i]) * 4096 + cS[i];
#pragma unroll
  for (int j = 0; j < 2; ++j)
    BgS[j] = (const char*)B + (size_t)(col0 + rS[j]) * 4096 + cS[j];
  const int dst = tid * 16;

#define STAGE(buf, kt) do {                                                      \
    const int kb = (kt) * 128;                                                   \
    char* lb = lds + (buf) * 24576;                                              \
    _Pragma("unroll")                                                            \
    for (int i = 0; i < 4; ++i)                                                  \
      __builtin_amdgcn_global_load_lds(                                          \
          (const __attribute__((address_space(1))) unsigned*)(AgS[i] + kb),      \
          (__attribute__((address_space(3))) unsigned*)(lb + i * 4096 + dst),    \
          16, 0, 0);                                                             \
    _Pragma("unroll")                                                            \
    for (int j = 0; j < 2; ++j)                                                  \
      __builtin_amdgcn_global_load_lds(                                          \
          (const __attribute__((address_space(1))) unsigned*)(BgS[j] + kb),      \
          (__attribute__((address_space(3))) unsigned*)(lb + 16384 + j * 4096 + dst), \
          16, 0, 0);                                                             \
  } while (0)

  // counted wait: tolerate the 6 loads just issued; everything older is done.
#define WAIT6_BAR() do {                                   \
    asm volatile("s_waitcnt vmcnt(6)" ::: "memory");       \
    __builtin_amdgcn_sched_barrier(0);                     \
    __builtin_amdgcn_s_barrier();                          \
  } while (0)
#define POST_BAR() do {                                    \
    __builtin_amdgcn_sched_barrier(0);                     \
    __builtin_amdgcn_s_barrier();                          \
  } while (0)

  // ---- fragment read addressing (swizzled) ----
  const int l15 = lane & 15;
  const int q16 = (lane >> 4) * 16;        // 16B sub-chunk within 32-k step
  const int swz = (l15 & 7) << 4;          // row&7 == l15&7 (row offsets %8==0)
  const int ck0 = q16 ^ swz;               // kk=0 byte col (swizzled)
  const int ck1 = (64 + q16) ^ swz;        // kk=1
  const int aRow = (wr * 64 + l15) * 128;  // byte row base for A frags
  const int bRow = (wc * 32 + l15) * 128;  // byte row base for B frags

  f32x4 acc[4][2] = {};

  auto compute = [&](const int buf) {
    const char* ab = lds + buf * 24576;
    const char* bb = ab + 16384;
    bf16x8 a0[4], a1[4], b0[2], b1[2];
#pragma unroll
    for (int m = 0; m < 4; ++m) {
      a0[m] = *(const bf16x8*)(ab + aRow + m * 2048 + ck0);
      a1[m] = *(const bf16x8*)(ab + aRow + m * 2048 + ck1);
    }
#pragma unroll
    for (int n = 0; n < 2; ++n) {
      b0[n] = *(const bf16x8*)(bb + bRow + n * 2048 + ck0);
      b1[n] = *(const bf16x8*)(bb + bRow + n * 2048 + ck1);
    }
#pragma unroll
    for (int m = 0; m < 4; ++m)
#pragma unroll
      for (int n = 0; n < 2; ++n) {
        acc[m][n] = __builtin_amdgcn_mfma_f32_16x16x32_bf16(a0[m], b0[n], acc[m][n], 0, 0, 0);
        acc[m][n] = __builtin_amdgcn_mfma_f32_16x16x32_bf16(a1[m], b1[n], acc[m][n], 0, 0, 0);
      }
  };

  STAGE(0, 0);
#pragma unroll 1
  for (int t = 0; t < 30; t += 2) {
    STAGE(1, t + 1);
    WAIT6_BAR();          // waits tile t's loads; t+1's stay in flight
    compute(0);
    POST_BAR();           // all waves done reading buf0 before next overwrite
    STAGE(0, t + 2);
    WAIT6_BAR();
    compute(1);
    POST_BAR();
  }
  STAGE(1, 31);
  WAIT6_BAR();
  compute(0);             // tile 30
  POST_BAR();
  asm volatile("s_waitcnt vmcnt(0)" ::: "memory");
  __builtin_amdgcn_sched_barrier(0);
  __builtin_amdgcn_s_barrier();
  compute(1);             // tile 31

  // epilogue: C/D layout col=lane&15, row=(lane>>4)*4+reg  [m89 verified]
  const int rb = row0 + wr * 64 + (lane >> 4) * 4;
#pragma unroll
  for (int n = 0; n < 2; ++n) {
    const int j = col0 + wc * 32 + n * 16 + l15;
    const float bv = bias[j];
#pragma unroll
    for (int m = 0; m < 4; ++m)
#pragma unroll
      for (int r = 0; r < 4; ++r)
        C[(size_t)(rb + m * 16 + r) * NMAT + j] = acc[m][n][r] + bv;
  }
#undef STAGE
#undef WAIT6_BAR
#undef POST_BAR
}

extern "C" void kernel_launch(void* const* d_in, const int* in_sizes, int n_in,
                              void* d_out, int out_size, void* d_ws, size_t ws_size,
                              hipStream_t stream) {
  const float* x  = (const float*)d_in[0];
  const float* w  = (const float*)d_in[1];
  const float* bs = (const float*)d_in[2];
  float* out = (float*)d_out;

  uint2* xd = (uint2*)d_ws;                       // 2048x2048 bf16 = 8MB
  uint2* wd = xd + (NMAT * (size_t)NMAT / 4);     // next 8MB

  qdq_kernel<<<dim3(8192), dim3(256), 0, stream>>>(x, xd, w, wd);

  dim3 grid(NMAT / 64, NMAT / 128);
  gemm_kernel<<<grid, dim3(256), 0, stream>>>((const __bf16*)xd, (const __bf16*)wd,
                                              bs, out);
}